// Round 8
// baseline (105.021 us; speedup 1.0000x reference)
//
#include <hip/hip_runtime.h>
#include <math.h>

#define T_UTT 50
#define H_DIM 512
#define B_DIM 4096
#define NWAVES 16
#define NT_PW 4      // ceil(50/16): waves 0-1 have 4 t's, waves 2-15 have 3
#define NBLK 256     // persistent blocks, 1 per CU
#define GENS 16      // 256 * 16 = 4096 = B_DIM

typedef float f32x4 __attribute__((ext_vector_type(4)));

__device__ __forceinline__ float dot8(f32x4 a0, f32x4 a1, f32x4 b0, f32x4 b1) {
    float s = 0.f;
#pragma unroll
    for (int j = 0; j < 4; ++j) s += a0[j] * b0[j];
#pragma unroll
    for (int j = 0; j < 4; ++j) s += a1[j] * b1[j];
    return s;
}

// One pipeline step: issue next-gen loads into (nu,nq), then compute current
// gen from (cu,cq). Cross-generation LDS reuse is fenced by the 3 barriers:
// all reads of s_score/s_w/s_q/s_part for gen g complete before the writing
// phase of gen g+1 can be reached (each write phase sits behind a barrier that
// the reading threads must also pass).
// NOTE: every use of the g parameter MUST be parenthesized — R7's failure was
// `g * NBLK` expanding as `g + 1 * NBLK` for the odd-step invocation.
#define STEP(cu0, cu1, cq0, cq1, nu0, nu1, nq0, nq1, g)                          \
    {                                                                            \
        /* ---- prefetch generation g+1 (streams under ALL of gen g) ---- */     \
        if ((g) + 1 < GENS) {                                                    \
            const int bn = ((g) + 1) * NBLK + k;                                 \
            const f32x4* qp = reinterpret_cast<const f32x4*>(                    \
                Q + (size_t)bn * H_DIM + h0);                                    \
            nq0 = qp[0]; nq1 = qp[1];                                            \
            _Pragma("unroll")                                                    \
            for (int i = 0; i < NT_PW; ++i) {                                    \
                const int t = wave + NWAVES * i;                                 \
                if (t < T_UTT) {                                                 \
                    const f32x4* up = reinterpret_cast<const f32x4*>(            \
                        U + ((size_t)t * B_DIM + bn) * H_DIM + h0);              \
                    nu0[i] = up[0]; nu1[i] = up[1];                              \
                }                                                                \
            }                                                                    \
        }                                                                        \
        /* ---- dots + norms for gen g ---- */                                   \
        _Pragma("unroll")                                                        \
        for (int i = 0; i < NT_PW; ++i) {                                        \
            const int t = wave + NWAVES * i;                                     \
            if (t < T_UTT) {                                                     \
                float d = dot8(cq0, cq1, cu0[i], cu1[i]);                        \
                float n = dot8(cu0[i], cu1[i], cu0[i], cu1[i]);                  \
                _Pragma("unroll")                                                \
                for (int m = 32; m; m >>= 1) {                                   \
                    d += __shfl_xor(d, m, 64);                                   \
                    n += __shfl_xor(n, m, 64);                                   \
                }                                                                \
                if (lane == 0) s_score[t] = d * rsqrtf(n);                       \
            }                                                                    \
        }                                                                        \
        __syncthreads(); /* A */                                                 \
        if (wave == 0) {                                                         \
            float qn = dot8(cq0, cq1, cq0, cq1);                                 \
            _Pragma("unroll")                                                    \
            for (int m = 32; m; m >>= 1) qn += __shfl_xor(qn, m, 64);            \
            const float q_inv = rsqrtf(qn);                                      \
            *reinterpret_cast<f32x4*>(&s_q[h0])     = cq0;                       \
            *reinterpret_cast<f32x4*>(&s_q[h0 + 4]) = cq1;                       \
            float v = (lane < T_UTT) ? s_score[lane] * q_inv                     \
                                     : ((lane == T_UTT) ? 1.0f : -INFINITY);     \
            float mx = v;                                                        \
            _Pragma("unroll")                                                    \
            for (int m = 32; m; m >>= 1) mx = fmaxf(mx, __shfl_xor(mx, m, 64));  \
            float e = __expf(v - mx);                                            \
            float sum = e;                                                       \
            _Pragma("unroll")                                                    \
            for (int m = 32; m; m >>= 1) sum += __shfl_xor(sum, m, 64);          \
            if (lane <= T_UTT) s_w[lane] = e / sum;                              \
        }                                                                        \
        __syncthreads(); /* B */                                                 \
        {                                                                        \
            float acc[8] = {0.f, 0.f, 0.f, 0.f, 0.f, 0.f, 0.f, 0.f};             \
            _Pragma("unroll")                                                    \
            for (int i = 0; i < NT_PW; ++i) {                                    \
                const int t = wave + NWAVES * i;                                 \
                if (t < T_UTT) {                                                 \
                    const float w = s_w[t];                                      \
                    acc[0] += w * cu0[i][0]; acc[1] += w * cu0[i][1];            \
                    acc[2] += w * cu0[i][2]; acc[3] += w * cu0[i][3];            \
                    acc[4] += w * cu1[i][0]; acc[5] += w * cu1[i][1];            \
                    acc[6] += w * cu1[i][2]; acc[7] += w * cu1[i][3];            \
                }                                                                \
            }                                                                    \
            f32x4* sp = reinterpret_cast<f32x4*>(&s_part[wave][h0]);             \
            sp[0] = (f32x4){acc[0], acc[1], acc[2], acc[3]};                     \
            sp[1] = (f32x4){acc[4], acc[5], acc[6], acc[7]};                     \
        }                                                                        \
        __syncthreads(); /* C */                                                 \
        if (tid < H_DIM) {                                                       \
            float o = s_w[T_UTT] * s_q[tid];                                     \
            _Pragma("unroll")                                                    \
            for (int w = 0; w < NWAVES; ++w) o += s_part[w][tid];                \
            Out[(size_t)((g) * NBLK + k) * H_DIM + tid] = o;                     \
        }                                                                        \
    }

// 1024 threads = 16 waves, persistent over 16 generations, 1 block per CU.
// __launch_bounds__(1024, 4): 4 waves/EU -> 16 waves/CU, VGPR cap 128
// (double-buffered u 64 + q 16 + acc 8 + temps ~ 110 total).
__global__ __launch_bounds__(1024, 4) void wseq_attn(const float* __restrict__ Q,
                                                     const float* __restrict__ U,
                                                     float* __restrict__ Out) {
    const int k0   = blockIdx.x;
    // XCD-chunked bijective swizzle (256 % 8 == 0): XCD x owns contiguous
    // k-range [x*32, (x+1)*32) -> concurrent blocks on one XCD read adjacent
    // 2KB b-rows -> contiguous L2/DRAM streams per generation.
    const int k    = (k0 & 7) * (NBLK / 8) + (k0 >> 3);
    const int tid  = threadIdx.x;
    const int lane = tid & 63;
    const int wave = tid >> 6;
    const int h0   = lane << 3;   // 8 floats per lane, 64 lanes = 512 = H_DIM

    __shared__ float s_score[T_UTT];
    __shared__ float s_w[T_UTT + 1];
    __shared__ float s_q[H_DIM];
    __shared__ float s_part[NWAVES][H_DIM];

    // double-buffered per-thread state (named, statically indexed)
    f32x4 uA0[NT_PW], uA1[NT_PW], qA0, qA1;
    f32x4 uB0[NT_PW], uB1[NT_PW], qB0, qB1;

    // ---- prologue: load generation 0 into buffer A ----
    {
        const int b = k;  // g = 0
        const f32x4* qp = reinterpret_cast<const f32x4*>(Q + (size_t)b * H_DIM + h0);
        qA0 = qp[0]; qA1 = qp[1];
#pragma unroll
        for (int i = 0; i < NT_PW; ++i) {
            const int t = wave + NWAVES * i;
            if (t < T_UTT) {
                const f32x4* up = reinterpret_cast<const f32x4*>(
                    U + ((size_t)t * B_DIM + b) * H_DIM + h0);
                uA0[i] = up[0]; uA1[i] = up[1];
            }
        }
    }

#pragma unroll 1
    for (int g = 0; g < GENS; g += 2) {
        STEP(uA0, uA1, qA0, qA1, uB0, uB1, qB0, qB1, g);
        STEP(uB0, uB1, qB0, qB1, uA0, uA1, qA0, qA1, g + 1);
    }
}

extern "C" void kernel_launch(void* const* d_in, const int* in_sizes, int n_in,
                              void* d_out, int out_size, void* d_ws, size_t ws_size,
                              hipStream_t stream) {
    const float* Q = (const float*)d_in[0];   // [B, H]
    const float* U = (const float*)d_in[1];   // [T, B, H]
    float* Out = (float*)d_out;               // [B, H]
    wseq_attn<<<dim3(NBLK), dim3(1024), 0, stream>>>(Q, U, Out);
}

// Round 9
// 76.746 us; speedup vs baseline: 1.3684x; 1.3684x over previous
//
#include <hip/hip_runtime.h>
#include <math.h>

#define T_UTT 50
#define H_DIM 512
#define B_DIM 4096
#define GRP 32     // threads (lanes) per b — one half-wave group
#define NB 8       // b's per 256-thread block
#define NFL 4      // float4s per thread: H_DIM / GRP / 4

typedef float f32x4 __attribute__((ext_vector_type(4)));

// One t-step: group-reduced dot & norm, exact fixed-shift softmax term
// (cosine <= 1 makes shift-by-1 an exact stabilizer), accumulate.
// Macro (not function) so u/acc/q stay statically-indexed registers.
#define COMPUTE(u)                                                      \
    {                                                                   \
        float d = 0.f, n = 0.f;                                         \
        _Pragma("unroll")                                               \
        for (int j = 0; j < NFL; ++j) {                                 \
            _Pragma("unroll")                                           \
            for (int c = 0; c < 4; ++c) {                               \
                d += q[j][c] * u[j][c];                                 \
                n += u[j][c] * u[j][c];                                 \
            }                                                           \
        }                                                               \
        _Pragma("unroll")                                               \
        for (int m = 16; m; m >>= 1) {                                  \
            d += __shfl_xor(d, m, GRP);                                 \
            n += __shfl_xor(n, m, GRP);                                 \
        }                                                               \
        const float e = __expf(d * rsqrtf(n) * q_inv - 1.0f);           \
        lsum += e;                                                      \
        _Pragma("unroll")                                               \
        for (int j = 0; j < NFL; ++j) {                                 \
            _Pragma("unroll")                                           \
            for (int c = 0; c < 4; ++c) acc[j][c] += e * u[j][c];       \
        }                                                               \
    }

// 256 threads = 8 groups of 32; group owns one b. NO LDS, NO barriers:
// the t-loop streams with loads always in flight (nothing drains vmcnt).
__global__ __launch_bounds__(256, 4) void wseq_attn(const float* __restrict__ Q,
                                                    const float* __restrict__ U,
                                                    float* __restrict__ Out) {
    const int tid = threadIdx.x;
    const int g   = tid & (GRP - 1);          // lane within group
    const int bl  = tid >> 5;                 // which b of this block
    const int b   = blockIdx.x * NB + bl;

    // thread's slice: float4 indices g + j*GRP  (512 B contiguous per group per j)
    const f32x4* qp = reinterpret_cast<const f32x4*>(Q + (size_t)b * H_DIM) + g;
    f32x4 q[NFL];
#pragma unroll
    for (int j = 0; j < NFL; ++j) q[j] = qp[j * GRP];

    // ||q||^2 via group butterfly (all 32 lanes get it)
    float qn = 0.f;
#pragma unroll
    for (int j = 0; j < NFL; ++j)
        qn += q[j][0]*q[j][0] + q[j][1]*q[j][1] + q[j][2]*q[j][2] + q[j][3]*q[j][3];
#pragma unroll
    for (int m = 16; m; m >>= 1) qn += __shfl_xor(qn, m, GRP);
    const float q_inv = rsqrtf(qn);

    const f32x4*  ub      = reinterpret_cast<const f32x4*>(U + (size_t)b * H_DIM) + g;
    const size_t  tstride = (size_t)B_DIM * H_DIM / 4;   // t-stride in f32x4 units

    f32x4 acc[NFL];
#pragma unroll
    for (int j = 0; j < NFL; ++j) acc[j] = (f32x4){0.f, 0.f, 0.f, 0.f};
    float lsum = 0.f;

    // register double-buffer, statically indexed (uA = even t, uB = odd t)
    f32x4 uA[NFL], uB[NFL];
#pragma unroll
    for (int j = 0; j < NFL; ++j) uA[j] = ub[j * GRP];   // t = 0

#pragma unroll 1
    for (int t = 0; t < T_UTT; t += 2) {
        {   // prefetch t+1 (always exists: T_UTT even, t <= 48)
            const f32x4* p = ub + (size_t)(t + 1) * tstride;
#pragma unroll
            for (int j = 0; j < NFL; ++j) uB[j] = p[j * GRP];
        }
        COMPUTE(uA);                                     // t
        if (t + 2 < T_UTT) {                             // prefetch t+2
            const f32x4* p = ub + (size_t)(t + 2) * tstride;
#pragma unroll
            for (int j = 0; j < NFL; ++j) uA[j] = p[j * GRP];
        }
        COMPUTE(uB);                                     // t+1
    }

    // finalize: query joins with weight exp(1-1)=1
    const float inv_l = 1.0f / (lsum + 1.0f);
    f32x4* op = reinterpret_cast<f32x4*>(Out + (size_t)b * H_DIM) + g;
#pragma unroll
    for (int j = 0; j < NFL; ++j) {
        f32x4 o;
#pragma unroll
        for (int c = 0; c < 4; ++c) o[c] = (acc[j][c] + q[j][c]) * inv_l;
        op[j * GRP] = o;
    }
}

extern "C" void kernel_launch(void* const* d_in, const int* in_sizes, int n_in,
                              void* d_out, int out_size, void* d_ws, size_t ws_size,
                              hipStream_t stream) {
    const float* Q = (const float*)d_in[0];   // [B, H]
    const float* U = (const float*)d_in[1];   // [T, B, H]
    float* Out = (float*)d_out;               // [B, H]
    wseq_attn<<<dim3(B_DIM / NB), dim3(256), 0, stream>>>(Q, U, Out);
}

// Round 10
// 75.599 us; speedup vs baseline: 1.3892x; 1.0152x over previous
//
#include <hip/hip_runtime.h>
#include <math.h>

#define T_UTT 50
#define H_DIM 512
#define B_DIM 4096
#define GRP 32     // threads (lanes) per b — one half-wave group
#define NB 8       // b's per 256-thread block
#define NFL 4      // float4s per thread: H_DIM / GRP / 4

typedef float f32x4 __attribute__((ext_vector_type(4)));

// Pair t-step: two utterances at once. The four reduction chains
// (d0,n0,d1,n1) are interleaved so their swizzle latencies overlap (ILP 4).
// exp shift by the exact bound 1.0 (cosine <= 1) -> no max pass needed.
#define PAIR(ua, ub)                                                    \
    {                                                                   \
        float d0 = 0.f, n0 = 0.f, d1 = 0.f, n1 = 0.f;                   \
        _Pragma("unroll")                                               \
        for (int j = 0; j < NFL; ++j) {                                 \
            _Pragma("unroll")                                           \
            for (int c = 0; c < 4; ++c) {                               \
                d0 += q[j][c] * ua[j][c];                               \
                n0 += ua[j][c] * ua[j][c];                              \
                d1 += q[j][c] * ub[j][c];                               \
                n1 += ub[j][c] * ub[j][c];                              \
            }                                                           \
        }                                                               \
        _Pragma("unroll")                                               \
        for (int m = 16; m; m >>= 1) {                                  \
            const float td0 = __shfl_xor(d0, m, GRP);                   \
            const float tn0 = __shfl_xor(n0, m, GRP);                   \
            const float td1 = __shfl_xor(d1, m, GRP);                   \
            const float tn1 = __shfl_xor(n1, m, GRP);                   \
            d0 += td0; n0 += tn0; d1 += td1; n1 += tn1;                 \
        }                                                               \
        const float e0 = __expf(d0 * rsqrtf(n0) * q_inv - 1.0f);        \
        const float e1 = __expf(d1 * rsqrtf(n1) * q_inv - 1.0f);        \
        lsum += e0 + e1;                                                \
        _Pragma("unroll")                                               \
        for (int j = 0; j < NFL; ++j) {                                 \
            _Pragma("unroll")                                           \
            for (int c = 0; c < 4; ++c)                                 \
                acc[j][c] += e0 * ua[j][c] + e1 * ub[j][c];             \
        }                                                               \
    }

#define LOADPAIR(ua, ub, t)                                             \
    {                                                                   \
        const f32x4* pa = ub_base + (size_t)(t) * tstride;              \
        const f32x4* pb = ub_base + (size_t)((t) + 1) * tstride;        \
        _Pragma("unroll")                                               \
        for (int j = 0; j < NFL; ++j) {                                 \
            ua[j] = pa[j * GRP];                                        \
            ub[j] = pb[j * GRP];                                        \
        }                                                               \
    }

// 256 threads = 8 groups of 32; group owns one b. No LDS, no barriers:
// loads stay in flight across the whole t-loop (nothing drains vmcnt).
__global__ __launch_bounds__(256, 4) void wseq_attn(const float* __restrict__ Q,
                                                    const float* __restrict__ U,
                                                    float* __restrict__ Out) {
    const int tid = threadIdx.x;
    const int g   = tid & (GRP - 1);          // lane within group
    const int bl  = tid >> 5;                 // which b of this block
    const int b   = blockIdx.x * NB + bl;

    // thread's slice: float4 indices g + j*GRP (512 B contiguous per group per j)
    const f32x4* qp = reinterpret_cast<const f32x4*>(Q + (size_t)b * H_DIM) + g;
    f32x4 q[NFL];
#pragma unroll
    for (int j = 0; j < NFL; ++j) q[j] = qp[j * GRP];

    // ||q||^2 via group butterfly (all 32 lanes get it)
    float qn = 0.f;
#pragma unroll
    for (int j = 0; j < NFL; ++j)
        qn += q[j][0]*q[j][0] + q[j][1]*q[j][1] + q[j][2]*q[j][2] + q[j][3]*q[j][3];
#pragma unroll
    for (int m = 16; m; m >>= 1) qn += __shfl_xor(qn, m, GRP);
    const float q_inv = rsqrtf(qn);

    const f32x4* ub_base = reinterpret_cast<const f32x4*>(U + (size_t)b * H_DIM) + g;
    const size_t tstride = (size_t)B_DIM * H_DIM / 4;   // t-stride in f32x4 units

    f32x4 acc[NFL];
#pragma unroll
    for (int j = 0; j < NFL; ++j) acc[j] = (f32x4){0.f, 0.f, 0.f, 0.f};
    float lsum = 0.f;

    // 4-buffer rotation, statically indexed: (uA,uB) computes while (uC,uD) loads
    f32x4 uA[NFL], uB[NFL], uC[NFL], uD[NFL];
    LOADPAIR(uA, uB, 0);

    // main loop: t = 0,4,...,44 (12 iters, 48 t's); tail pair (48,49) after
#pragma unroll 1
    for (int t = 0; t < T_UTT - 2; t += 4) {
        LOADPAIR(uC, uD, t + 2);
        PAIR(uA, uB);
        if (t + 4 < T_UTT) LOADPAIR(uA, uB, t + 4);
        PAIR(uC, uD);
    }
    PAIR(uA, uB);   // t = 48, 49

    // finalize: query joins with weight exp(1-1) = 1
    const float inv_l = 1.0f / (lsum + 1.0f);
    f32x4* op = reinterpret_cast<f32x4*>(Out + (size_t)b * H_DIM) + g;
#pragma unroll
    for (int j = 0; j < NFL; ++j) {
        f32x4 o;
#pragma unroll
        for (int c = 0; c < 4; ++c) o[c] = (acc[j][c] + q[j][c]) * inv_l;
        op[j * GRP] = o;
    }
}

extern "C" void kernel_launch(void* const* d_in, const int* in_sizes, int n_in,
                              void* d_out, int out_size, void* d_ws, size_t ws_size,
                              hipStream_t stream) {
    const float* Q = (const float*)d_in[0];   // [B, H]
    const float* U = (const float*)d_in[1];   // [T, B, H]
    float* Out = (float*)d_out;               // [B, H]
    wseq_attn<<<dim3(B_DIM / NB), dim3(256), 0, stream>>>(Q, U, Out);
}